// Round 1
// baseline (247.417 us; speedup 1.0000x reference)
//
#include <hip/hip_runtime.h>

#define BB 64
#define TT 512
#define DD 768
#define LL 5
#define NSEQ (2 * BB)          // 128
#define NTOK (NSEQ * TT)       // 65536

// ---------------------------------------------------------------------------
// Kernel A: logits[tok][l] = x[tok][:] . W[:][l] + b[l]
// One wave (64 lanes) per token; lane covers d = lane*4 + q + p*256 (p=0..2).
// W held in registers (12 rows x 5 = 60 floats/lane), x loaded as float4.
// ---------------------------------------------------------------------------
__global__ __launch_bounds__(256) void k_logits(const float* __restrict__ x,
                                                const float* __restrict__ W,
                                                const float* __restrict__ bias,
                                                float* __restrict__ logits) {
    const int lane = threadIdx.x & 63;
    const int wid  = blockIdx.x * (blockDim.x >> 6) + (threadIdx.x >> 6);
    const int nw   = gridDim.x * (blockDim.x >> 6);

    float wreg[3][4][LL];
#pragma unroll
    for (int p = 0; p < 3; ++p)
#pragma unroll
        for (int q = 0; q < 4; ++q) {
            const int d = p * 256 + lane * 4 + q;
#pragma unroll
            for (int l = 0; l < LL; ++l) wreg[p][q][l] = W[d * LL + l];
        }
    float breg[LL];
#pragma unroll
    for (int l = 0; l < LL; ++l) breg[l] = bias[l];

    for (int tok = wid; tok < NTOK; tok += nw) {
        const float4* xp = reinterpret_cast<const float4*>(x + (size_t)tok * DD);
        float acc[LL] = {0.f, 0.f, 0.f, 0.f, 0.f};
#pragma unroll
        for (int p = 0; p < 3; ++p) {
            float4 v = xp[p * 64 + lane];
#pragma unroll
            for (int l = 0; l < LL; ++l) {
                acc[l] += v.x * wreg[p][0][l];
                acc[l] += v.y * wreg[p][1][l];
                acc[l] += v.z * wreg[p][2][l];
                acc[l] += v.w * wreg[p][3][l];
            }
        }
#pragma unroll
        for (int off = 32; off > 0; off >>= 1) {
#pragma unroll
            for (int l = 0; l < LL; ++l) acc[l] += __shfl_xor(acc[l], off, 64);
        }
        if (lane == 0) {
#pragma unroll
            for (int l = 0; l < LL; ++l)
                logits[(size_t)tok * LL + l] = acc[l] + breg[l];
        }
    }
}

// ---------------------------------------------------------------------------
// Kernel B: per-sequence CRF scans. One block (1 wave) per sequence.
// Lanes 0..4 own states; alpha broadcast via __shfl each step.
// Backpointers packed 5x3 bits into u16 in LDS; backtrace on lane 0.
// ---------------------------------------------------------------------------
__global__ __launch_bounds__(64) void k_scan(const float* __restrict__ logits,
                                             const int* __restrict__ label,
                                             const int* __restrict__ seqlen,
                                             const float* __restrict__ trans,
                                             float* __restrict__ score,
                                             float* __restrict__ lognorm,
                                             int* __restrict__ tags) {
    const int n    = blockIdx.x;        // 0..127
    const int lane = threadIdx.x;       // 0..63
    __shared__ unsigned short bp[TT];
    __shared__ float tr[LL * LL];
    if (lane < LL * LL) tr[lane] = trans[lane];
    __syncthreads();

    const int sl = seqlen[n & (BB - 1)];
    const float* lg = logits + (size_t)n * TT * LL;
    const int jj = (lane < LL) ? lane : 0;   // this lane's state (clamped)

    float tcol[LL];
#pragma unroll
    for (int i = 0; i < LL; ++i) tcol[i] = tr[i * LL + jj];

    float a_ln[LL], a_de[LL];
#pragma unroll
    for (int i = 0; i < LL; ++i) { a_ln[i] = lg[i]; a_de[i] = lg[i]; }

    const int* lab = label + (n & (BB - 1)) * TT;
    const bool second = (n >= BB);
    int ptag = 0;
    float sc = 0.f;
    if (lane == 0) {
        const int l0 = lab[0];
        ptag = (l0 > 0) ? (second ? l0 + 1 : 1) : 0;
        sc = lg[ptag];                 // t=0 unary (always active, seqlen>=2)
    }

    for (int t = 1; t < TT; ++t) {
        const bool act = (t < sl);
        const float xt = lg[t * LL + jj];

        // --- log-norm update: new[j] = x + logsumexp_i(a[i] + tr[i][j]) ---
        const float v0 = a_ln[0] + tcol[0];
        const float v1 = a_ln[1] + tcol[1];
        const float v2 = a_ln[2] + tcol[2];
        const float v3 = a_ln[3] + tcol[3];
        const float v4 = a_ln[4] + tcol[4];
        const float m = fmaxf(fmaxf(fmaxf(v0, v1), fmaxf(v2, v3)), v4);
        const float s = __expf(v0 - m) + __expf(v1 - m) + __expf(v2 - m) +
                        __expf(v3 - m) + __expf(v4 - m);
        float nln = xt + m + __logf(s);

        // --- viterbi forward: max/argmax_i (first-occurrence ties) ---
        float dbest = a_de[0] + tcol[0];
        int bi = 0;
#pragma unroll
        for (int i = 1; i < LL; ++i) {
            const float c = a_de[i] + tcol[i];
            if (c > dbest) { dbest = c; bi = i; }
        }
        float nde = xt + dbest;

        if (!act) { nln = a_ln[jj]; nde = a_de[jj]; bi = jj; }

        // broadcast new alphas from lanes 0..4 to all lanes
#pragma unroll
        for (int i = 0; i < LL; ++i) a_ln[i] = __shfl(nln, i, 64);
#pragma unroll
        for (int i = 0; i < LL; ++i) a_de[i] = __shfl(nde, i, 64);

        unsigned w = 0;
#pragma unroll
        for (int i = 0; i < LL; ++i)
            w |= ((unsigned)__shfl(bi, i, 64) & 7u) << (3 * i);

        if (lane == 0) {
            bp[t] = (unsigned short)w;
            if (act) {
                const int lt = lab[t];
                const int tg = (lt > 0) ? (second ? lt + 1 : 1) : 0;
                sc += lg[t * LL + tg] + tr[ptag * LL + tg];
                ptag = tg;
            }
        }
    }

    if (lane == 0) {
        // final logsumexp for log-norm
        float m = fmaxf(fmaxf(fmaxf(a_ln[0], a_ln[1]), fmaxf(a_ln[2], a_ln[3])), a_ln[4]);
        float s = 0.f;
#pragma unroll
        for (int i = 0; i < LL; ++i) s += __expf(a_ln[i] - m);
        lognorm[n] = m + __logf(s);
        score[n]   = sc;

        // backtrace
        int tg = 0;
        float best = a_de[0];
#pragma unroll
        for (int i = 1; i < LL; ++i)
            if (a_de[i] > best) { best = a_de[i]; tg = i; }
        int* to = tags + n * TT;
        to[TT - 1] = tg;
        for (int t = TT - 1; t >= 1; --t) {
            tg = (bp[t] >> (3 * tg)) & 7;
            to[t - 1] = tg;
        }
    }
}

// ---------------------------------------------------------------------------
// Kernel C: viterbi output + per-block accuracy counts (no atomics).
// ---------------------------------------------------------------------------
__global__ __launch_bounds__(256) void k_combine(const int* __restrict__ tags,
                                                 const int* __restrict__ label,
                                                 const int* __restrict__ seqlen,
                                                 float* __restrict__ out,
                                                 int* __restrict__ accpart) {
    const int idx = blockIdx.x * 256 + threadIdx.x;   // 0..32767
    const int bb  = idx >> 9;                         // / 512
    const int t   = idx & 511;
    const int v1  = tags[idx];                        // sequence bb
    const int v2  = tags[idx + BB * TT];              // sequence bb + 64
    const int vit = (v1 == 0 || v2 == 0) ? 0 : (v2 - 1);
    out[idx] = (float)vit;
    const int ok = ((vit == label[idx]) && (t < seqlen[bb])) ? 1 : 0;

    __shared__ int sd[256];
    sd[threadIdx.x] = ok;
    __syncthreads();
    for (int s = 128; s > 0; s >>= 1) {
        if (threadIdx.x < s) sd[threadIdx.x] += sd[threadIdx.x + s];
        __syncthreads();
    }
    if (threadIdx.x == 0) accpart[blockIdx.x] = sd[0];
}

// ---------------------------------------------------------------------------
// Kernel D: loss = mean(lognorm - score); acc = sum(ok) / sum(seqlen).
// ---------------------------------------------------------------------------
__global__ __launch_bounds__(128) void k_final(const float* __restrict__ score,
                                               const float* __restrict__ lognorm,
                                               const int* __restrict__ accpart,
                                               const int* __restrict__ seqlen,
                                               float* __restrict__ out) {
    __shared__ float sf[128];
    __shared__ int s1[128];
    __shared__ int s2[128];
    const int tid = threadIdx.x;
    sf[tid] = lognorm[tid] - score[tid];
    s1[tid] = accpart[tid];
    s2[tid] = (tid < BB) ? seqlen[tid] : 0;
    __syncthreads();
    for (int s = 64; s > 0; s >>= 1) {
        if (tid < s) {
            sf[tid] += sf[tid + s];
            s1[tid] += s1[tid + s];
            s2[tid] += s2[tid + s];
        }
        __syncthreads();
    }
    if (tid == 0) {
        out[BB * TT]     = sf[0] / (float)NSEQ;        // loss
        out[BB * TT + 1] = (float)s1[0] / (float)s2[0]; // acc
    }
}

// ---------------------------------------------------------------------------
extern "C" void kernel_launch(void* const* d_in, const int* in_sizes, int n_in,
                              void* d_out, int out_size, void* d_ws, size_t ws_size,
                              hipStream_t stream) {
    const float* x      = (const float*)d_in[0];
    const int*   label  = (const int*)d_in[1];
    const int*   seqlen = (const int*)d_in[2];
    const float* W      = (const float*)d_in[3];
    const float* bias   = (const float*)d_in[4];
    const float* trans  = (const float*)d_in[5];
    float* out = (float*)d_out;
    char*  ws  = (char*)d_ws;

    // ws layout (all 4B aligned):
    //   [0, 1310720)            logits  float[NTOK*LL]
    //   [1310720, +512)         score   float[128]
    //   [1311232, +512)         lognorm float[128]
    //   [1311744, +262144)      tags    int[NSEQ*TT]
    //   [1573888, +512)         accpart int[128]
    float* ws_logits  = (float*)(ws);
    float* ws_score   = (float*)(ws + 1310720);
    float* ws_lognorm = (float*)(ws + 1311232);
    int*   ws_tags    = (int*)(ws + 1311744);
    int*   ws_acc     = (int*)(ws + 1573888);

    hipLaunchKernelGGL(k_logits, dim3(2048), dim3(256), 0, stream,
                       x, W, bias, ws_logits);
    hipLaunchKernelGGL(k_scan, dim3(NSEQ), dim3(64), 0, stream,
                       ws_logits, label, seqlen, trans,
                       ws_score, ws_lognorm, ws_tags);
    hipLaunchKernelGGL(k_combine, dim3(128), dim3(256), 0, stream,
                       ws_tags, label, seqlen, out, ws_acc);
    hipLaunchKernelGGL(k_final, dim3(1), dim3(128), 0, stream,
                       ws_score, ws_lognorm, ws_acc, seqlen, out);
}

// Round 3
// 86.642 us; speedup vs baseline: 2.8556x; 2.8556x over previous
//
#include <hip/hip_runtime.h>

#define BB 64
#define TT 512
#define DD 768
#define LL 5
#define NSEQ 128
#define NTOK 65536
#define NEG_INF (-1e30f)
#define IDENT_W 0x4688u   // bp word encoding j->j (0|1<<3|2<<6|3<<9|4<<12)

// ---------------------------------------------------------------------------
// Kernel A: logits = x @ W + b. One thread per token; W transposed in LDS
// (broadcast b128 reads). No cross-lane ops. HBM-bound by x (201 MB).
// ---------------------------------------------------------------------------
__global__ __launch_bounds__(256) void k_logits(const float* __restrict__ x,
                                                const float* __restrict__ W,
                                                const float* __restrict__ bias,
                                                float* __restrict__ logits) {
    __shared__ float sW[LL * DD];
    __shared__ float sb[LL];
    for (int i = threadIdx.x; i < LL * DD; i += 256) {
        const int l = i / DD, d = i - l * DD;
        sW[i] = W[d * LL + l];
    }
    if (threadIdx.x < LL) sb[threadIdx.x] = bias[threadIdx.x];
    __syncthreads();

    const int tok = blockIdx.x * 256 + threadIdx.x;   // grid 256 -> exact cover
    const float4* xp = reinterpret_cast<const float4*>(x + (size_t)tok * DD);
    float a0 = sb[0], a1 = sb[1], a2 = sb[2], a3 = sb[3], a4 = sb[4];
#pragma unroll 4
    for (int q = 0; q < DD / 4; ++q) {
        const float4 v  = xp[q];
        const float4 w0 = *reinterpret_cast<const float4*>(&sW[0 * DD + 4 * q]);
        const float4 w1 = *reinterpret_cast<const float4*>(&sW[1 * DD + 4 * q]);
        const float4 w2 = *reinterpret_cast<const float4*>(&sW[2 * DD + 4 * q]);
        const float4 w3 = *reinterpret_cast<const float4*>(&sW[3 * DD + 4 * q]);
        const float4 w4 = *reinterpret_cast<const float4*>(&sW[4 * DD + 4 * q]);
        a0 += v.x * w0.x + v.y * w0.y + v.z * w0.z + v.w * w0.w;
        a1 += v.x * w1.x + v.y * w1.y + v.z * w1.z + v.w * w1.w;
        a2 += v.x * w2.x + v.y * w2.y + v.z * w2.z + v.w * w2.w;
        a3 += v.x * w3.x + v.y * w3.y + v.z * w3.z + v.w * w3.w;
        a4 += v.x * w4.x + v.y * w4.y + v.z * w4.z + v.w * w4.w;
    }
    float* o = logits + (size_t)tok * LL;
    o[0] = a0; o[1] = a1; o[2] = a2; o[3] = a3; o[4] = a4;
}

// ---------------------------------------------------------------------------
// Kernel B: chunked semiring scans. Blocks 0..127: log-norm (lse semiring),
// blocks 128..255: viterbi (max-plus). 32 chunks x 16 steps; chunk products
// in parallel, 32-step serial chunk-scan, register-resident backpointers.
// ---------------------------------------------------------------------------
__global__ __launch_bounds__(256) void k_scan2(const float* __restrict__ logits,
                                               const int* __restrict__ seqlen,
                                               const float* __restrict__ trans,
                                               float* __restrict__ lognorm,
                                               int* __restrict__ tags) {
    __shared__ float s_lg[TT * LL + 8];   // +pad: t=512 dummy reads
    __shared__ float s_P[32 * 25];
    __shared__ float s_A[33 * 5];
    __shared__ float s_tr[25];
    __shared__ float s_etr[25];
    __shared__ unsigned s_mapw[32];
    __shared__ int s_B[33];
    __shared__ int s_tags[TT];

    const int tid  = threadIdx.x;
    const int role = blockIdx.x >> 7;        // 0 = lognorm, 1 = viterbi
    const int n    = blockIdx.x & 127;
    const int sl   = seqlen[n & (BB - 1)];
    const float* lg = logits + (size_t)n * TT * LL;

    for (int i = tid; i < TT * LL + 8; i += 256)
        s_lg[i] = (i < TT * LL) ? lg[i] : 0.f;
    if (tid < 25) { const float tv = trans[tid]; s_tr[tid] = tv; s_etr[tid] = __expf(tv); }
    __syncthreads();

    if (role == 0) {
        // ---------------- log-norm ----------------
        if (tid < 160) {
            const int c = tid / 5, r = tid - 5 * c;
            float p[5];
#pragma unroll
            for (int j = 0; j < 5; ++j) p[j] = (j == r) ? 0.f : NEG_INF;
#pragma unroll
            for (int i = 0; i < 16; ++i) {
                const int t = c * 16 + 1 + i;
                const bool act = t < sl;
                const float m = fmaxf(fmaxf(fmaxf(p[0], p[1]), fmaxf(p[2], p[3])), p[4]);
                float e[5];
#pragma unroll
                for (int k = 0; k < 5; ++k) e[k] = __expf(p[k] - m);
                float nv[5];
#pragma unroll
                for (int j = 0; j < 5; ++j) {
                    float s = e[0] * s_etr[j];
#pragma unroll
                    for (int k = 1; k < 5; ++k) s += e[k] * s_etr[k * 5 + j];
                    nv[j] = m + __logf(s) + s_lg[t * 5 + j];
                }
#pragma unroll
                for (int j = 0; j < 5; ++j) p[j] = act ? nv[j] : p[j];
            }
#pragma unroll
            for (int j = 0; j < 5; ++j) s_P[c * 25 + r * 5 + j] = __expf(p[j]);
        }
        __syncthreads();
        if (tid == 0) {
            float a[5];
#pragma unroll
            for (int j = 0; j < 5; ++j) a[j] = s_lg[j];
            for (int c = 0; c < 32; ++c) {
                const float m = fmaxf(fmaxf(fmaxf(a[0], a[1]), fmaxf(a[2], a[3])), a[4]);
                float e[5];
#pragma unroll
                for (int k = 0; k < 5; ++k) e[k] = __expf(a[k] - m);
                float nv[5];
#pragma unroll
                for (int j = 0; j < 5; ++j) {
                    float s = e[0] * s_P[c * 25 + j];
#pragma unroll
                    for (int k = 1; k < 5; ++k) s += e[k] * s_P[c * 25 + k * 5 + j];
                    nv[j] = m + __logf(s);
                }
#pragma unroll
                for (int j = 0; j < 5; ++j) a[j] = nv[j];
            }
            const float m = fmaxf(fmaxf(fmaxf(a[0], a[1]), fmaxf(a[2], a[3])), a[4]);
            float s = 0.f;
#pragma unroll
            for (int j = 0; j < 5; ++j) s += __expf(a[j] - m);
            lognorm[n] = m + __logf(s);
        }
    } else {
        // ---------------- viterbi ----------------
        if (tid < 160) {
            const int c = tid / 5, r = tid - 5 * c;
            float p[5];
#pragma unroll
            for (int j = 0; j < 5; ++j) p[j] = (j == r) ? 0.f : NEG_INF;
#pragma unroll
            for (int i = 0; i < 16; ++i) {
                const int t = c * 16 + 1 + i;
                const bool act = t < sl;
                float nv[5];
#pragma unroll
                for (int j = 0; j < 5; ++j) {
                    float b = p[0] + s_tr[j];
#pragma unroll
                    for (int k = 1; k < 5; ++k) b = fmaxf(b, p[k] + s_tr[k * 5 + j]);
                    nv[j] = b + s_lg[t * 5 + j];
                }
#pragma unroll
                for (int j = 0; j < 5; ++j) p[j] = act ? nv[j] : p[j];
            }
#pragma unroll
            for (int j = 0; j < 5; ++j) s_P[c * 25 + r * 5 + j] = p[j];
        }
        __syncthreads();
        if (tid == 0) {                       // serial chunk-scan: boundary alphas
            float a[5];
#pragma unroll
            for (int j = 0; j < 5; ++j) { a[j] = s_lg[j]; s_A[j] = a[j]; }
            for (int c = 0; c < 32; ++c) {
                float nv[5];
#pragma unroll
                for (int j = 0; j < 5; ++j) {
                    float b = a[0] + s_P[c * 25 + j];
#pragma unroll
                    for (int k = 1; k < 5; ++k) b = fmaxf(b, a[k] + s_P[c * 25 + k * 5 + j]);
                    nv[j] = b;
                }
#pragma unroll
                for (int j = 0; j < 5; ++j) { a[j] = nv[j]; s_A[(c + 1) * 5 + j] = a[j]; }
            }
        }
        __syncthreads();
        unsigned bpw[16];                     // per-chunk backpointers, registers
        if (tid < 32) {
            const int c = tid;
            float a[5];
#pragma unroll
            for (int j = 0; j < 5; ++j) a[j] = s_A[c * 5 + j];
#pragma unroll
            for (int i = 0; i < 16; ++i) {
                const int t = c * 16 + 1 + i;
                const bool act = t < sl;
                float nv[5]; int gi[5];
#pragma unroll
                for (int j = 0; j < 5; ++j) {
                    float b = a[0] + s_tr[j]; int g = 0;
#pragma unroll
                    for (int k = 1; k < 5; ++k) {
                        const float cn = a[k] + s_tr[k * 5 + j];
                        if (cn > b) { b = cn; g = k; }
                    }
                    nv[j] = b + s_lg[t * 5 + j]; gi[j] = g;
                }
                const unsigned w = (unsigned)gi[0] | ((unsigned)gi[1] << 3) |
                                   ((unsigned)gi[2] << 6) | ((unsigned)gi[3] << 9) |
                                   ((unsigned)gi[4] << 12);
                bpw[i] = act ? w : IDENT_W;
#pragma unroll
                for (int j = 0; j < 5; ++j) a[j] = act ? nv[j] : a[j];
            }
            // compose chunk map (end-state -> start-state), pure VALU
            int m[5] = {0, 1, 2, 3, 4};
#pragma unroll
            for (int i = 15; i >= 0; --i) {
                const unsigned w = bpw[i];
#pragma unroll
                for (int j = 0; j < 5; ++j) m[j] = (int)((w >> (3 * m[j])) & 7u);
            }
            s_mapw[c] = (unsigned)m[0] | ((unsigned)m[1] << 3) | ((unsigned)m[2] << 6) |
                        ((unsigned)m[3] << 9) | ((unsigned)m[4] << 12);
        }
        __syncthreads();
        if (tid == 0) {                       // boundary tags via map chain (VALU)
            float b = s_A[32 * 5 + 0]; int lt = 0;
#pragma unroll
            for (int j = 1; j < 5; ++j) {
                const float cn = s_A[32 * 5 + j];
                if (cn > b) { b = cn; lt = j; }
            }
            unsigned w[32];
#pragma unroll
            for (int c = 0; c < 32; ++c) w[c] = s_mapw[c];
            int bc = lt; s_B[32] = lt;
#pragma unroll
            for (int c = 31; c >= 0; --c) { bc = (int)((w[c] >> (3 * bc)) & 7u); s_B[c] = bc; }
        }
        __syncthreads();
        if (tid < 32) {                       // emit tags from register bps
            int cur = s_B[tid + 1];
#pragma unroll
            for (int i = 15; i >= 0; --i) {
                cur = (int)((bpw[i] >> (3 * cur)) & 7u);
                s_tags[tid * 16 + i] = cur;
            }
        }
        __syncthreads();
        int* to = tags + n * TT;
        for (int i = tid; i < TT; i += 256) to[i] = s_tags[i];
    }
}

// ---------------------------------------------------------------------------
// Kernel C: sequence score, parallel over t. One block per sequence.
// ---------------------------------------------------------------------------
__global__ __launch_bounds__(256) void k_score(const float* __restrict__ logits,
                                               const int* __restrict__ label,
                                               const int* __restrict__ seqlen,
                                               const float* __restrict__ trans,
                                               float* __restrict__ score) {
    const int n = blockIdx.x, tid = threadIdx.x;
    __shared__ float s_tr[25];
    __shared__ float sred[256];
    if (tid < 25) s_tr[tid] = trans[tid];
    __syncthreads();
    const int sl = seqlen[n & (BB - 1)];
    const bool sec = (n >= BB);
    const int* lab = label + (n & (BB - 1)) * TT;
    const float* lg = logits + (size_t)n * TT * LL;
    float s = 0.f;
    for (int t = tid; t < TT; t += 256) {
        if (t < sl) {
            const int l = lab[t];
            const int tg = (l > 0) ? (sec ? l + 1 : 1) : 0;
            s += lg[t * LL + tg];
            if (t >= 1) {
                const int lp = lab[t - 1];
                const int tp = (lp > 0) ? (sec ? lp + 1 : 1) : 0;
                s += s_tr[tp * LL + tg];
            }
        }
    }
    sred[tid] = s;
    __syncthreads();
    for (int st = 128; st > 0; st >>= 1) {
        if (tid < st) sred[tid] += sred[tid + st];
        __syncthreads();
    }
    if (tid == 0) score[n] = sred[0];
}

// ---------------------------------------------------------------------------
// Kernel D: viterbi output + per-block accuracy counts.
// ---------------------------------------------------------------------------
__global__ __launch_bounds__(256) void k_combine(const int* __restrict__ tags,
                                                 const int* __restrict__ label,
                                                 const int* __restrict__ seqlen,
                                                 float* __restrict__ out,
                                                 int* __restrict__ accpart) {
    const int idx = blockIdx.x * 256 + threadIdx.x;   // 0..32767
    const int bb  = idx >> 9;
    const int t   = idx & 511;
    const int v1  = tags[idx];
    const int v2  = tags[idx + BB * TT];
    const int vit = (v1 == 0 || v2 == 0) ? 0 : (v2 - 1);
    out[idx] = (float)vit;
    const int ok = ((vit == label[idx]) && (t < seqlen[bb])) ? 1 : 0;

    __shared__ int sd[256];
    sd[threadIdx.x] = ok;
    __syncthreads();
    for (int s = 128; s > 0; s >>= 1) {
        if (threadIdx.x < s) sd[threadIdx.x] += sd[threadIdx.x + s];
        __syncthreads();
    }
    if (threadIdx.x == 0) accpart[blockIdx.x] = sd[0];
}

// ---------------------------------------------------------------------------
// Kernel E: final scalars.
// ---------------------------------------------------------------------------
__global__ __launch_bounds__(128) void k_final(const float* __restrict__ score,
                                               const float* __restrict__ lognorm,
                                               const int* __restrict__ accpart,
                                               const int* __restrict__ seqlen,
                                               float* __restrict__ out) {
    __shared__ float sf[128];
    __shared__ int s1[128];
    __shared__ int s2[128];
    const int tid = threadIdx.x;
    sf[tid] = lognorm[tid] - score[tid];
    s1[tid] = accpart[tid];
    s2[tid] = (tid < BB) ? seqlen[tid] : 0;
    __syncthreads();
    for (int s = 64; s > 0; s >>= 1) {
        if (tid < s) { sf[tid] += sf[tid + s]; s1[tid] += s1[tid + s]; s2[tid] += s2[tid + s]; }
        __syncthreads();
    }
    if (tid == 0) {
        out[BB * TT]     = sf[0] / (float)NSEQ;
        out[BB * TT + 1] = (float)s1[0] / (float)s2[0];
    }
}

// ---------------------------------------------------------------------------
extern "C" void kernel_launch(void* const* d_in, const int* in_sizes, int n_in,
                              void* d_out, int out_size, void* d_ws, size_t ws_size,
                              hipStream_t stream) {
    const float* x      = (const float*)d_in[0];
    const int*   label  = (const int*)d_in[1];
    const int*   seqlen = (const int*)d_in[2];
    const float* W      = (const float*)d_in[3];
    const float* bias   = (const float*)d_in[4];
    const float* trans  = (const float*)d_in[5];
    float* out = (float*)d_out;
    char*  ws  = (char*)d_ws;

    float* ws_logits  = (float*)(ws);                 // 1,310,720 B
    float* ws_score   = (float*)(ws + 1310720);       // 512 B
    float* ws_lognorm = (float*)(ws + 1311232);       // 512 B
    int*   ws_tags    = (int*)(ws + 1311744);         // 262,144 B
    int*   ws_acc     = (int*)(ws + 1573888);         // 512 B

    hipLaunchKernelGGL(k_logits, dim3(256), dim3(256), 0, stream,
                       x, W, bias, ws_logits);
    hipLaunchKernelGGL(k_scan2, dim3(256), dim3(256), 0, stream,
                       ws_logits, seqlen, trans, ws_lognorm, ws_tags);
    hipLaunchKernelGGL(k_score, dim3(NSEQ), dim3(256), 0, stream,
                       ws_logits, label, seqlen, trans, ws_score);
    hipLaunchKernelGGL(k_combine, dim3(128), dim3(256), 0, stream,
                       ws_tags, label, seqlen, out, ws_acc);
    hipLaunchKernelGGL(k_final, dim3(1), dim3(128), 0, stream,
                       ws_score, ws_lognorm, ws_acc, seqlen, out);
}